// Round 2
// baseline (262.907 us; speedup 1.0000x reference)
//
#include <hip/hip_runtime.h>

// Conv2Central: reference = stencil applied 4x (batch flips cancel).
// Composed separable 5-tap filter, coeffs (1+0.5z)^4 = {1, 2, 1.5, 0.5, 0.0625}.
// y[n,i,j] = sum_{di,dj} c[di]*c[dj]*x[n,i+di,j+dj], zero past the boundary.

#define N_IMG 32
#define H_IMG 1024
#define W_IMG 1024
#define RPT 8   // output rows per thread

__global__ __launch_bounds__(256) void stencil4_kernel(const float* __restrict__ in,
                                                       float* __restrict__ out) {
    const float c0 = 1.0f, c1 = 2.0f, c2 = 1.5f, c3 = 0.5f, c4 = 0.0625f;

    const int j0 = threadIdx.x * 4;          // 256 threads * 4 cols = full 1024-wide row
    const int i0 = blockIdx.x * RPT;         // row strip
    const int n  = blockIdx.y;

    const float* img = in  + (size_t)n * H_IMG * W_IMG;
    float*       o   = out + (size_t)n * H_IMG * W_IMG;

    // Row-filtered intermediates for rows i0 .. i0+RPT+3
    float4 f[RPT + 4];

    #pragma unroll
    for (int r = 0; r < RPT + 4; ++r) {
        const int i = i0 + r;
        float4 a = make_float4(0.f, 0.f, 0.f, 0.f);
        float4 b = make_float4(0.f, 0.f, 0.f, 0.f);
        if (i < H_IMG) {
            a = *reinterpret_cast<const float4*>(img + (size_t)i * W_IMG + j0);
            if (j0 + 4 < W_IMG) {
                b = *reinterpret_cast<const float4*>(img + (size_t)i * W_IMG + j0 + 4);
            }
        }
        // 5-tap forward row filter on cols j0..j0+3 (needs x[j0..j0+7])
        float4 t;
        t.x = c0*a.x + c1*a.y + c2*a.z + c3*a.w + c4*b.x;
        t.y = c0*a.y + c1*a.z + c2*a.w + c3*b.x + c4*b.y;
        t.z = c0*a.z + c1*a.w + c2*b.x + c3*b.y + c4*b.z;
        t.w = c0*a.w + c1*b.x + c2*b.y + c3*b.z + c4*b.w;
        f[r] = t;
    }

    // 5-tap forward column filter
    #pragma unroll
    for (int r = 0; r < RPT; ++r) {
        float4 y;
        y.x = c0*f[r].x + c1*f[r+1].x + c2*f[r+2].x + c3*f[r+3].x + c4*f[r+4].x;
        y.y = c0*f[r].y + c1*f[r+1].y + c2*f[r+2].y + c3*f[r+3].y + c4*f[r+4].y;
        y.z = c0*f[r].z + c1*f[r+1].z + c2*f[r+2].z + c3*f[r+3].z + c4*f[r+4].z;
        y.w = c0*f[r].w + c1*f[r+1].w + c2*f[r+2].w + c3*f[r+3].w + c4*f[r+4].w;
        *reinterpret_cast<float4*>(o + (size_t)(i0 + r) * W_IMG + j0) = y;
    }
}

extern "C" void kernel_launch(void* const* d_in, const int* in_sizes, int n_in,
                              void* d_out, int out_size, void* d_ws, size_t ws_size,
                              hipStream_t stream) {
    const float* img = (const float*)d_in[0];
    float*       out = (float*)d_out;

    dim3 grid(H_IMG / RPT, N_IMG);   // 128 x 32 = 4096 blocks
    dim3 block(256);
    stencil4_kernel<<<grid, block, 0, stream>>>(img, out);
}

// Round 8
// 229.200 us; speedup vs baseline: 1.1471x; 1.1471x over previous
//
#include <hip/hip_runtime.h>

// Conv2Central: reference = stencil applied 4x (batch flips are on the batch
// axis and commute with the per-slice 2D stencil, so they cancel).
// Composed separable 5-tap filter: (1+0.5z)^4 = {1, 2, 1.5, 0.5, 0.0625}.
//
// This version: async global->LDS staging (global_load_lds, 16B width) to get
// a deep VMEM queue with zero VGPR cost, 2-stage counted vmcnt waits to
// overlap compute with the load tail, sliding-window column filter in regs.

#define N_IMG 32
#define H_IMG 1024
#define W_IMG 1024
#define R_OUT 8                    // output rows per block
#define NROWS (R_OUT + 4)          // input rows staged per block = 12
#define ROWF  (W_IMG + 8)          // floats per LDS row (8-float zero tail)
#define ROWB  (ROWF * 4)           // 4128 bytes per LDS row

// size arg must be a literal -> macro, not function
#define GLOAD16(gp, lp) __builtin_amdgcn_global_load_lds(                     \
    (const __attribute__((address_space(1))) void*)(gp),                      \
    (__attribute__((address_space(3))) void*)(lp), 16, 0, 0)

__device__ __forceinline__ float4 rowfilt(const float* __restrict__ row) {
    const float c0 = 1.0f, c1 = 2.0f, c2 = 1.5f, c3 = 0.5f, c4 = 0.0625f;
    float4 a = *reinterpret_cast<const float4*>(row);      // ds_read_b128
    float4 b = *reinterpret_cast<const float4*>(row + 4);  // ds_read_b128
    float4 t;
    t.x = c0*a.x + c1*a.y + c2*a.z + c3*a.w + c4*b.x;
    t.y = c0*a.y + c1*a.z + c2*a.w + c3*b.x + c4*b.y;
    t.z = c0*a.z + c1*a.w + c2*b.x + c3*b.y + c4*b.z;
    t.w = c0*a.w + c1*b.x + c2*b.y + c3*b.z + c4*b.w;
    return t;
}

__device__ __forceinline__ float4 colcomb(float4 w0, float4 w1, float4 w2,
                                          float4 w3, float4 t) {
    const float c0 = 1.0f, c1 = 2.0f, c2 = 1.5f, c3 = 0.5f, c4 = 0.0625f;
    float4 y;
    y.x = c0*w0.x + c1*w1.x + c2*w2.x + c3*w3.x + c4*t.x;
    y.y = c0*w0.y + c1*w1.y + c2*w2.y + c3*w3.y + c4*t.y;
    y.z = c0*w0.z + c1*w1.z + c2*w2.z + c3*w3.z + c4*t.z;
    y.w = c0*w0.w + c1*w1.w + c2*w2.w + c3*w3.w + c4*t.w;
    return y;
}

__global__ __launch_bounds__(256) void stencil4_lds(const float* __restrict__ in,
                                                    float* __restrict__ out) {
    __shared__ float tile[NROWS * ROWF];   // 12 * 4128 B = 49,536 B -> 3 blocks/CU

    const int tid = threadIdx.x;
    const int i0  = blockIdx.x * R_OUT;
    const int n   = blockIdx.y;
    const float* img = in  + (size_t)n * H_IMG * W_IMG;
    float*       o   = out + (size_t)n * H_IMG * W_IMG;

    // Zero the 8-float tail of every staged row (horizontal zero-pad).
    if (tid < NROWS * 2) {
        int q = tid >> 1, s = tid & 1;
        *reinterpret_cast<float4*>(&tile[q * ROWF + W_IMG + s * 4]) =
            make_float4(0.f, 0.f, 0.f, 0.f);
    }
    // Zero rows that fall past the bottom boundary (last strip only;
    // condition is block-uniform). Rows 0..7 are always in-bounds.
    #pragma unroll
    for (int q = R_OUT; q < NROWS; ++q) {
        if (i0 + q >= H_IMG) {
            *reinterpret_cast<float4*>(&tile[q * ROWF + tid * 4]) =
                make_float4(0.f, 0.f, 0.f, 0.f);
        }
    }

    // Issue async global->LDS staging: one 4 KB row per block-wide op,
    // 12 deep, zero VGPR cost. LDS dest = wave-uniform base (+ lane*16 by HW).
    const int wave_byte = (tid >> 6) * 1024;          // wave segment in a row
    const int lane_col  = (tid & 63) * 4 + (tid >> 6) * 256;  // == tid*4
    #pragma unroll
    for (int q = 0; q < NROWS; ++q) {
        if (i0 + q < H_IMG) {
            GLOAD16(img + (size_t)(i0 + q) * W_IMG + lane_col,
                    (char*)tile + q * ROWB + wave_byte);
        }
    }

    // Stage A: rows 0..7 resident -> compute output rows 0..3.
    // All strips except the last issued 12 loads (wait leaves 4 in flight);
    // the last strip issued exactly 8 (drain all). Block-uniform branch.
    if (i0 + NROWS - 1 < H_IMG) {
        asm volatile("s_waitcnt vmcnt(4) lgkmcnt(0)\n\ts_barrier" ::: "memory");
    } else {
        asm volatile("s_waitcnt vmcnt(0) lgkmcnt(0)\n\ts_barrier" ::: "memory");
    }

    const int j0 = tid * 4;
    float4 w0 = rowfilt(&tile[0 * ROWF + j0]);
    float4 w1 = rowfilt(&tile[1 * ROWF + j0]);
    float4 w2 = rowfilt(&tile[2 * ROWF + j0]);
    float4 w3 = rowfilt(&tile[3 * ROWF + j0]);

    #pragma unroll
    for (int r = 0; r < 4; ++r) {
        float4 t = rowfilt(&tile[(r + 4) * ROWF + j0]);
        float4 y = colcomb(w0, w1, w2, w3, t);
        *reinterpret_cast<float4*>(o + (size_t)(i0 + r) * W_IMG + j0) = y;
        w0 = w1; w1 = w2; w2 = w3; w3 = t;
    }

    // Stage B: remaining rows resident -> compute output rows 4..7.
    asm volatile("s_waitcnt vmcnt(0) lgkmcnt(0)\n\ts_barrier" ::: "memory");

    #pragma unroll
    for (int r = 4; r < R_OUT; ++r) {
        float4 t = rowfilt(&tile[(r + 4) * ROWF + j0]);
        float4 y = colcomb(w0, w1, w2, w3, t);
        *reinterpret_cast<float4*>(o + (size_t)(i0 + r) * W_IMG + j0) = y;
        w0 = w1; w1 = w2; w2 = w3; w3 = t;
    }
}

extern "C" void kernel_launch(void* const* d_in, const int* in_sizes, int n_in,
                              void* d_out, int out_size, void* d_ws, size_t ws_size,
                              hipStream_t stream) {
    const float* img = (const float*)d_in[0];
    float*       out = (float*)d_out;

    dim3 grid(H_IMG / R_OUT, N_IMG);   // 128 x 32 = 4096 blocks
    dim3 block(256);
    stencil4_lds<<<grid, block, 0, stream>>>(img, out);
}